// Round 10
// baseline (2020.328 us; speedup 1.0000x reference)
//
#include <hip/hip_runtime.h>
#include <math.h>

// ---------------------------------------------------------------------------
// AdvancedMixConsole: 64 tracks x 131072 samples.
//   gain -> 6 biquads (chunk-parallel linear recurrence, 12-dim state)
//        -> compressor: parallel static gain; serial smoother as 16-sample
//           composed max-affine chain (17 slopes aa^j ar^(16-j)); one block
//           per track: wave0 = chain with VOLATILE ds_reads (native vector
//           type, not HIP float4!) + empty-asm register pins, ping-pong 2+2;
//           waves1-3 = global->LDS producers (double-buffered chunks).
//        -> pan/mix (parallel, two-stage).
// ---------------------------------------------------------------------------

#define S_LEN 131072
#define NTR   64
#define CCH   256          // chunks (biquad phase)
#define LCH   512          // samples per chunk
#define SMW   16           // smoother window
#define NST2  8192         // 16-sample windows per track
#define WPC2  32           // windows per biquad chunk
#define SCH2  128          // k_smooth steps per LDS chunk
#define NCH2  (NST2/SCH2)  // 64 LDS chunks
#define RECQ  5            // float4s per step record (17 slopes + pad)

typedef float v2f __attribute__((ext_vector_type(2)));
typedef float v4f __attribute__((ext_vector_type(4)));   // native: volatile-loadable

// ws offsets in floats (total ~79.3 MB)
#define OFF_Y    0ull              // [131072][64]      EQ output y, sample-major
#define OFF_CI   8388608ull        // [64][NST2][20]    composed intercepts I[0..16]+pad
#define OFF_TV   8388608ull        // [131072][64]      tv = y*gain (ALIASES CI)
#define OFF_QB   18874368ull       // [NST2][64]        boundary q after each window
#define OFF_W    19398656ull       // [64][2]           cos/sin pan weights
#define OFF_COEF 19398784ull       // [64][32]          biquad coeffs
#define OFF_COMP 19400832ull       // [64][64]          compressor consts + 17 slopes
#define OFF_A    19404928ull       // [64][144]         cascade transition matrix
#define OFF_M    19414144ull       // [64][144]         A^LCH
#define OFF_F    19423360ull       // [64][CCH][12]     zero-init chunk finals
#define OFF_Z    19619968ull       // [64][CCH][12]     chunk init states

// ---------------------------------------------------------------------------
__global__ __launch_bounds__(64) void k_setup(const float* __restrict__ mp,
                                              float* __restrict__ ws) {
  int n = threadIdx.x;
  if (n >= NTR) return;
  const float* p = mp + n * 26;
  auto dn = [&](int i, double lo, double hi) { return (double)p[i] * (hi - lo) + lo; };

  double gain_db = dn(0, -24.0, 24.0);
  double glin = pow(10.0, gain_db / 20.0);
  const double nyq = 21050.0;  // 44100//2 - 1000

  double fg[6] = {dn(1,-24,24), dn(4,-24,24), dn(7,-24,24), dn(10,-24,24), dn(13,-24,24), dn(16,-24,24)};
  double ff[6] = {dn(2,20,2000), dn(5,80,2000), dn(8,2000,8000), dn(11,8000,12000), dn(14,12000,nyq), dn(17,6000,nyq)};
  double fq[6] = {dn(3,0.1,5), dn(6,0.1,5), dn(9,0.1,5), dn(12,0.1,5), dn(15,0.1,5), dn(18,0.1,5)};

  double B0[6], B1[6], B2[6], A1[6], A2[6];
  for (int k = 0; k < 6; k++) {
    double A  = pow(10.0, fg[k] / 40.0);
    double w0 = 2.0 * M_PI * ff[k] / 44100.0;
    double cw = cos(w0), sw = sin(w0);
    double al = sw / (2.0 * fq[k]);
    double sA = sqrt(A);
    double b0, b1, b2, a0, a1, a2;
    if (k == 0) {           // low shelf
      b0 = A*((A+1)-(A-1)*cw + 2*sA*al);
      b1 = 2*A*((A-1)-(A+1)*cw);
      b2 = A*((A+1)-(A-1)*cw - 2*sA*al);
      a0 = (A+1)+(A-1)*cw + 2*sA*al;
      a1 = -2*((A-1)+(A+1)*cw);
      a2 = (A+1)+(A-1)*cw - 2*sA*al;
    } else if (k == 5) {    // high shelf
      b0 = A*((A+1)+(A-1)*cw + 2*sA*al);
      b1 = -2*A*((A-1)+(A+1)*cw);
      b2 = A*((A+1)+(A-1)*cw - 2*sA*al);
      a0 = (A+1)-(A-1)*cw + 2*sA*al;
      a1 = 2*((A-1)-(A+1)*cw);
      a2 = (A+1)-(A-1)*cw - 2*sA*al;
    } else {                // peak
      b0 = 1 + al*A; b1 = -2*cw; b2 = 1 - al*A;
      a0 = 1 + al/A; a1 = -2*cw; a2 = 1 - al/A;
    }
    B0[k] = b0/a0; B1[k] = b1/a0; B2[k] = b2/a0; A1[k] = a1/a0; A2[k] = a2/a0;
  }
  // fold input gain into stage-0 numerator
  B0[0] *= glin; B1[0] *= glin; B2[0] *= glin;

  float* cf = ws + OFF_COEF + n * 32;
  for (int k = 0; k < 6; k++) {
    cf[k*5+0] = (float)B0[k]; cf[k*5+1] = (float)B1[k]; cf[k*5+2] = (float)B2[k];
    cf[k*5+3] = (float)A1[k]; cf[k*5+4] = (float)A2[k];
  }

  // compressor + pan constants
  double T = dn(19,-60,0), R = dn(20,1,10), atk = dn(21,1,1000), rel = dn(22,1,1000);
  double Kn = dn(23,3,24), mk = dn(24,0,24);
  double a_a = exp(-1.0 / (44100.0 * atk * 0.001));
  double a_r = exp(-1.0 / (44100.0 * rel * 0.001));
  double s   = (a_a < a_r) ? 1.0 : -1.0;     // q = s*p makes the recurrence pure-max
  double kca = s * (1.0 - a_a), kcr = s * (1.0 - a_r);
  double invR = 1.0 / R;
  const double K10 = 0.16609640474436813;    // log2(10)/20
  double theta = (double)p[25] * (M_PI / 2.0);

  float* cm = ws + OFF_COMP + n * 64;
  cm[0] = (float)a_a;  cm[1] = (float)a_r;  cm[2] = (float)kca; cm[3] = (float)kcr;
  cm[4] = (float)T;    cm[5] = (float)(Kn * 0.5);
  cm[6] = (float)(1.0 - invR);
  cm[7] = (float)((1.0 - invR) / (2.0 * Kn));
  cm[8] = (float)(mk * K10);   cm[9] = (float)(s * K10);
  cm[10] = (float)cos(theta);  cm[11] = (float)sin(theta);
  // 17 composed slopes aa^j * ar^(16-j), j = 0..16
  for (int j = 0; j <= 16; j++)
    cm[16+j] = (float)(pow(a_a, (double)j) * pow(a_r, (double)(16-j)));

  float* wp = ws + OFF_W + n*2;
  wp[0] = (float)cos(theta); wp[1] = (float)sin(theta);

  // homogeneous (x=0) cascade transition matrix, state = [s1_1,s2_1,...,s1_6,s2_6]
  double Am[12][12], yv[12], ny[12];
  for (int r = 0; r < 12; r++) { yv[r] = 0; for (int c = 0; c < 12; c++) Am[r][c] = 0; }
  for (int k = 0; k < 6; k++) {
    for (int c = 0; c < 12; c++) ny[c] = B0[k] * yv[c];
    ny[2*k] += 1.0;                                  // y_k = b0*y_{k-1} + s1_k
    for (int c = 0; c < 12; c++) Am[2*k][c]   = B1[k]*yv[c] - A1[k]*ny[c];
    Am[2*k][2*k+1] += 1.0;                           // + s2_k
    for (int c = 0; c < 12; c++) Am[2*k+1][c] = B2[k]*yv[c] - A2[k]*ny[c];
    for (int c = 0; c < 12; c++) yv[c] = ny[c];
  }
  float* Aw = ws + OFF_A + n * 144;
  for (int r = 0; r < 12; r++)
    for (int c = 0; c < 12; c++) Aw[r*12+c] = (float)Am[r][c];
}

// ---------------------------------------------------------------------------
__global__ __launch_bounds__(192) void k_matpow(float* __restrict__ ws) {
  __shared__ float As[144];
  int n = blockIdx.x, t = threadIdx.x;
  int r = t / 12, c = t % 12;
  if (t < 144) As[t] = ws[OFF_A + (size_t)n*144 + t];
  __syncthreads();
  for (int it = 0; it < 9; ++it) {   // A^(2^9) = A^LCH (LCH=512)
    float acc = 0.f;
    if (t < 144) {
      #pragma unroll
      for (int k = 0; k < 12; k++) acc += As[r*12+k] * As[k*12+c];
    }
    __syncthreads();
    if (t < 144) As[t] = acc;
    __syncthreads();
  }
  if (t < 144) ws[OFF_M + (size_t)n*144 + t] = As[t];
}

// ---------------------------------------------------------------------------
__device__ __forceinline__ void load_coefs(const float* cf, float* b0, v2f* bb, v2f* naa) {
  #pragma unroll
  for (int k = 0; k < 6; k++) {
    b0[k]  = cf[k*5+0];
    bb[k]  = (v2f){cf[k*5+1], cf[k*5+2]};
    naa[k] = (v2f){-cf[k*5+3], -cf[k*5+4]};
  }
}

__device__ __forceinline__ float cascade_step(float x, float* b0, v2f* bb, v2f* naa, v2f* st) {
  #pragma unroll
  for (int k = 0; k < 6; k++) {
    float y  = fmaf(b0[k], x, st[k].x);
    v2f upd  = __builtin_elementwise_fma(bb[k], (v2f){x, x}, (v2f){st[k].y, 0.f});
    st[k]    = __builtin_elementwise_fma(naa[k], (v2f){y, y}, upd);
    x = y;
  }
  return x;
}

// phase 1: zero-init chunk finals
__global__ __launch_bounds__(64) void k_phase1(const float* __restrict__ tracks,
                                               float* __restrict__ ws) {
  int j = blockIdx.x, n = threadIdx.x;
  float b0[6]; v2f bb[6], naa[6];
  load_coefs(ws + OFF_COEF + n*32, b0, bb, naa);
  v2f st[6];
  #pragma unroll
  for (int k = 0; k < 6; k++) st[k] = (v2f){0.f, 0.f};
  const float4* xp = (const float4*)(tracks + (size_t)n*S_LEN + (size_t)j*LCH);
  for (int i4 = 0; i4 < LCH/4; ++i4) {
    float4 xq = xp[i4];
    float xs[4] = {xq.x, xq.y, xq.z, xq.w};
    #pragma unroll
    for (int u = 0; u < 4; u++) (void)cascade_step(xs[u], b0, bb, naa, st);
  }
  float* f = ws + OFF_F + (size_t)n*(CCH*12) + (size_t)j*12;
  #pragma unroll
  for (int k = 0; k < 6; k++) { f[2*k] = st[k].x; f[2*k+1] = st[k].y; }
}

// serial scan of chunk-boundary states: z_{j+1} = M z_j + f_j
__global__ __launch_bounds__(64) void k_scanz(float* __restrict__ ws) {
  int n = threadIdx.x;
  float M[144];
  #pragma unroll
  for (int i = 0; i < 144; i++) M[i] = ws[OFF_M + (size_t)n*144 + i];
  float z[12];
  #pragma unroll
  for (int r = 0; r < 12; r++) z[r] = 0.f;
  const float* fb = ws + OFF_F + (size_t)n*(CCH*12);
  float*       zb = ws + OFF_Z + (size_t)n*(CCH*12);
  for (int j = 0; j < CCH; j++) {
    #pragma unroll
    for (int r = 0; r < 12; r++) zb[j*12+r] = z[r];
    float nz[12];
    #pragma unroll
    for (int r = 0; r < 12; r++) {
      float acc = fb[j*12+r];
      #pragma unroll
      for (int c = 0; c < 12; c++) acc = fmaf(M[r*12+c], z[c], acc);
      nz[r] = acc;
    }
    #pragma unroll
    for (int r = 0; r < 12; r++) z[r] = nz[r];
  }
}

// phase 3: correct-init EQ; per-sample static gain; per-16-sample-window
// composed max-affine intercepts I[0..16] (I[j] = best path with j attacks),
// written as 80B records [track][step][20] for k_smooth's uniform loads.
__global__ __launch_bounds__(64) void k_phase3(const float* __restrict__ tracks,
                                               float* __restrict__ ws) {
  int j = blockIdx.x, n = threadIdx.x;
  float b0[6]; v2f bb[6], naa[6];
  load_coefs(ws + OFF_COEF + n*32, b0, bb, naa);
  const float* cm = ws + OFF_COMP + n*64;
  float a_a = cm[0], a_r = cm[1], kca = cm[2], kcr = cm[3];
  float T = cm[4], hK = cm[5], cg1 = cm[6], cg2 = cm[7];
  v2f st[6];
  const float* zp = ws + OFF_Z + (size_t)n*(CCH*12) + (size_t)j*12;
  #pragma unroll
  for (int k = 0; k < 6; k++) st[k] = (v2f){zp[2*k], zp[2*k+1]};

  const float4* xp = (const float4*)(tracks + (size_t)n*S_LEN + (size_t)j*LCH);
  float* yb = ws + OFF_Y + (size_t)j*LCH*64 + n;                      // [sample][track]
  float* cw = ws + OFF_CI + ((size_t)n*NST2 + (size_t)j*WPC2)*20;     // [track][step][20]

  for (int w = 0; w < WPC2; ++w) {
    float I[17];
    I[0] = 0.f;
    #pragma unroll
    for (int jj = 1; jj < 17; ++jj) I[jj] = -1e30f;
    #pragma unroll
    for (int i4 = 0; i4 < 4; ++i4) {
      float4 xq = xp[w*4 + i4];
      float xs[4] = {xq.x, xq.y, xq.z, xq.w};
      #pragma unroll
      for (int u = 0; u < 4; ++u) {
        const int i = i4*4 + u;
        float y = cascade_step(xs[u], b0, bb, naa, st);
        yb[(w*16 + i)*64] = y;
        float v   = fabsf(y) + 1e-8f;
        float xdb = 6.020599913279624f * __log2f(v);
        float d   = xdb - T;
        float dk  = d + hK;
        float gg  = (d > hK) ? (cg1*d) : (cg2*dk*dk);
        gg = (d < -hK) ? 0.f : gg;
        float ca = kca*gg, cr = kcr*gg;
        // compose one sample into the window map (descending j, in place)
        #pragma unroll
        for (int jj = 16; jj >= 0; --jj) {
          if (jj <= i+1) {
            float up = (jj > 0) ? fmaf(a_a, I[jj-1], ca) : -1e30f;
            I[jj] = fmaxf(up, fmaf(a_r, I[jj], cr));
          }
        }
      }
    }
    float4* cq = (float4*)(cw + (size_t)w*20);
    cq[0] = make_float4(I[0],  I[1],  I[2],  I[3]);
    cq[1] = make_float4(I[4],  I[5],  I[6],  I[7]);
    cq[2] = make_float4(I[8],  I[9],  I[10], I[11]);
    cq[3] = make_float4(I[12], I[13], I[14], I[15]);
    cq[4] = make_float4(I[16], 0.f, 0.f, 0.f);
  }
}

// ---------------------------------------------------------------------------
// serial max-affine smoother. One 256-thread block per track:
//   wave 0  = chain: VOLATILE uniform ds_reads (native v4f — issue position
//             pinned vs volatile asm) + empty-asm "+v" pins (wait position +
//             VGPR residency forced). Ping-pong 2+2 steps: every load has
//             >=2 EVALs (~132 cyc) between issue and wait > 120 cyc LDS lat.
//   waves 1-3 = producers: stream CI global->LDS, double-buffered chunks.
#define VLOAD5(p0,p1,p2,p3,p4, IDX)                                          \
  p0 = *(volatile const v4f*)(Lb + (IDX)*RECQ + 0);                          \
  p1 = *(volatile const v4f*)(Lb + (IDX)*RECQ + 1);                          \
  p2 = *(volatile const v4f*)(Lb + (IDX)*RECQ + 2);                          \
  p3 = *(volatile const v4f*)(Lb + (IDX)*RECQ + 3);                          \
  p4 = *(volatile const v4f*)(Lb + (IDX)*RECQ + 4);

#define PIN10(a0,a1,a2,a3,a4, b0,b1,b2,b3,b4)                                \
  asm volatile("" : "+v"(a0),"+v"(a1),"+v"(a2),"+v"(a3),"+v"(a4),            \
                    "+v"(b0),"+v"(b1),"+v"(b2),"+v"(b3),"+v"(b4));

#define EVAL_STEP(A,B,C,D,E, LCL)                                            \
  {                                                                          \
    float t0  = fmaf(S0,q,A.x),  t1  = fmaf(S1,q,A.y);                       \
    float t2  = fmaf(S2,q,A.z),  t3  = fmaf(S3,q,A.w);                       \
    float t4  = fmaf(S4,q,B.x),  t5  = fmaf(S5,q,B.y);                       \
    float t6  = fmaf(S6,q,B.z),  t7  = fmaf(S7,q,B.w);                       \
    float t8  = fmaf(S8,q,C.x),  t9  = fmaf(S9,q,C.y);                       \
    float t10 = fmaf(S10,q,C.z), t11 = fmaf(S11,q,C.w);                      \
    float t12 = fmaf(S12,q,D.x), t13 = fmaf(S13,q,D.y);                      \
    float t14 = fmaf(S14,q,D.z), t15 = fmaf(S15,q,D.w);                      \
    float t16 = fmaf(S16,q,E.x);                                             \
    float m0 = fmaxf(fmaxf(t0,t1),t2);                                       \
    float m1 = fmaxf(fmaxf(t3,t4),t5);                                       \
    float m2 = fmaxf(fmaxf(t6,t7),t8);                                       \
    float m3 = fmaxf(fmaxf(t9,t10),t11);                                     \
    float m4 = fmaxf(fmaxf(t12,t13),t14);                                    \
    float m5 = fmaxf(fmaxf(t15,t16),m0);                                     \
    float mm = fmaxf(fmaxf(m1,m2),m3);                                       \
    q = fmaxf(fmaxf(m4,m5),mm);                                              \
    qs = (l == ((LCL) & 63)) ? q : qs;                                       \
  }

__global__ __launch_bounds__(256, 1) void k_smooth(const v4f* __restrict__ cp,
                                                   const float* __restrict__ cmv,
                                                   float* __restrict__ qb) {
  __shared__ v4f buf[2][SCH2*RECQ];         // 2 x 10KB
  const int n = blockIdx.x;
  const int tid = threadIdx.x;
  const int wave = tid >> 6, l = tid & 63;
  const v4f* __restrict__ base = cp + (size_t)n * NST2 * RECQ;

  // preload chunk 0 (all threads)
  for (int i = tid; i < SCH2*RECQ; i += 256) buf[0][i] = base[i];
  __syncthreads();

  const float* cm = cmv + n*64;
  const float S0  = cm[16], S1  = cm[17], S2  = cm[18], S3  = cm[19];
  const float S4  = cm[20], S5  = cm[21], S6  = cm[22], S7  = cm[23];
  const float S8  = cm[24], S9  = cm[25], S10 = cm[26], S11 = cm[27];
  const float S12 = cm[28], S13 = cm[29], S14 = cm[30], S15 = cm[31];
  const float S16 = cm[32];

  float q = 0.f, qs = 0.f;
  for (int c2 = 0; c2 < NCH2; ++c2) {
    if (wave != 0) {
      if (c2 + 1 < NCH2) {
        const v4f* src = base + (size_t)(c2+1)*SCH2*RECQ;
        v4f* dst = &buf[(c2+1) & 1][0];
        for (int i = tid - 64; i < SCH2*RECQ; i += 192) dst[i] = src[i];
      }
    } else {
      const v4f* Lb = &buf[c2 & 1][0];
      v4f Pa0,Pa1,Pa2,Pa3,Pa4, Pb0,Pb1,Pb2,Pb3,Pb4;
      v4f Na0,Na1,Na2,Na3,Na4, Nb0,Nb1,Nb2,Nb3,Nb4;
      VLOAD5(Pa0,Pa1,Pa2,Pa3,Pa4, 0)
      VLOAD5(Pb0,Pb1,Pb2,Pb3,Pb4, 1)
      VLOAD5(Na0,Na1,Na2,Na3,Na4, 2)
      VLOAD5(Nb0,Nb1,Nb2,Nb3,Nb4, 3)
      PIN10(Pa0,Pa1,Pa2,Pa3,Pa4, Pb0,Pb1,Pb2,Pb3,Pb4)
      for (int g = 0; g < SCH2 - 8; g += 4) {
        EVAL_STEP(Pa0,Pa1,Pa2,Pa3,Pa4, g+0)
        EVAL_STEP(Pb0,Pb1,Pb2,Pb3,Pb4, g+1)
        VLOAD5(Pa0,Pa1,Pa2,Pa3,Pa4, g+4)
        VLOAD5(Pb0,Pb1,Pb2,Pb3,Pb4, g+5)
        PIN10(Na0,Na1,Na2,Na3,Na4, Nb0,Nb1,Nb2,Nb3,Nb4)
        EVAL_STEP(Na0,Na1,Na2,Na3,Na4, g+2)
        EVAL_STEP(Nb0,Nb1,Nb2,Nb3,Nb4, g+3)
        VLOAD5(Na0,Na1,Na2,Na3,Na4, g+6)
        VLOAD5(Nb0,Nb1,Nb2,Nb3,Nb4, g+7)
        PIN10(Pa0,Pa1,Pa2,Pa3,Pa4, Pb0,Pb1,Pb2,Pb3,Pb4)
        if (((g+3) & 63) == 63) {
          const int h = c2*2 + ((g+3) >> 6);
          qb[(size_t)(h*64 + l)*64 + n] = qs;
        }
      }
      // tail: steps SCH2-8 .. SCH2-1
      {
        const int g = SCH2 - 8;
        EVAL_STEP(Pa0,Pa1,Pa2,Pa3,Pa4, g+0)
        EVAL_STEP(Pb0,Pb1,Pb2,Pb3,Pb4, g+1)
        PIN10(Na0,Na1,Na2,Na3,Na4, Nb0,Nb1,Nb2,Nb3,Nb4)
        EVAL_STEP(Na0,Na1,Na2,Na3,Na4, g+2)
        EVAL_STEP(Nb0,Nb1,Nb2,Nb3,Nb4, g+3)
        VLOAD5(Pa0,Pa1,Pa2,Pa3,Pa4, g+4)
        VLOAD5(Pb0,Pb1,Pb2,Pb3,Pb4, g+5)
        VLOAD5(Na0,Na1,Na2,Na3,Na4, g+6)
        VLOAD5(Nb0,Nb1,Nb2,Nb3,Nb4, g+7)
        PIN10(Pa0,Pa1,Pa2,Pa3,Pa4, Pb0,Pb1,Pb2,Pb3,Pb4)
        PIN10(Na0,Na1,Na2,Na3,Na4, Nb0,Nb1,Nb2,Nb3,Nb4)
        EVAL_STEP(Pa0,Pa1,Pa2,Pa3,Pa4, g+4)
        EVAL_STEP(Pb0,Pb1,Pb2,Pb3,Pb4, g+5)
        EVAL_STEP(Na0,Na1,Na2,Na3,Na4, g+6)
        EVAL_STEP(Nb0,Nb1,Nb2,Nb3,Nb4, g+7)
        qb[(size_t)((c2*2 + 1)*64 + l)*64 + n] = qs;
      }
    }
    __syncthreads();
  }
}

// tv = y * 10^((mk - p)/20): exact 16-step reconstruction from boundary q.
// lanes = tracks -> fully coalesced y/tv rows.
__global__ __launch_bounds__(256) void k_mix1(float* __restrict__ ws) {
  const int n  = threadIdx.x & 63;
  const int kk = blockIdx.x*4 + (threadIdx.x >> 6);
  const float* cm = ws + OFF_COMP + n*64;
  const float aa = cm[0], ar = cm[1], kca = cm[2], kcr = cm[3];
  const float T = cm[4], hK = cm[5], cg1 = cm[6], cg2 = cm[7];
  const float mkK = cm[8], sK = cm[9];
  const float* __restrict__ yb  = ws + OFF_Y;
  float* __restrict__       tvb = ws + OFF_TV;
  float q = (kk > 0) ? ws[OFF_QB + (size_t)(kk-1)*64 + n] : 0.f;
  #pragma unroll
  for (int i = 0; i < SMW; ++i) {
    float y = yb[(size_t)(kk*SMW + i)*64 + n];
    float v   = fabsf(y) + 1e-8f;
    float xdb = 6.020599913279624f * __log2f(v);
    float d   = xdb - T;
    float dk  = d + hK;
    float gg  = (d > hK) ? (cg1*d) : (cg2*dk*dk);
    gg = (d < -hK) ? 0.f : gg;
    q = fmaxf(fmaf(aa, q, kca*gg), fmaf(ar, q, kcr*gg));
    float sc = exp2f(fmaf(-sK, q, mkK));
    tvb[(size_t)(kk*SMW + i)*64 + n] = y * sc;
  }
}

// 16-track pan reduction -> out[b][2][S]
__global__ __launch_bounds__(256) void k_mix2(const float* __restrict__ ws,
                                              float* __restrict__ out) {
  const int b = threadIdx.x & 3;
  const int s = blockIdx.x*64 + (threadIdx.x >> 2);
  const float* __restrict__ tvb = ws + OFF_TV;
  const float2* __restrict__ wp = (const float2*)(ws + OFF_W);
  float accL = 0.f, accR = 0.f;
  const int n0 = b*16;
  #pragma unroll
  for (int t = 0; t < 16; ++t) {
    float tv = tvb[(size_t)s*64 + n0 + t];
    float2 w2 = wp[n0 + t];
    accL = fmaf(w2.x, tv, accL);
    accR = fmaf(w2.y, tv, accR);
  }
  out[(size_t)(b*2 + 0)*S_LEN + s] = accL;
  out[(size_t)(b*2 + 1)*S_LEN + s] = accR;
}

// ---------------------------------------------------------------------------
extern "C" void kernel_launch(void* const* d_in, const int* in_sizes, int n_in,
                              void* d_out, int out_size, void* d_ws, size_t ws_size,
                              hipStream_t stream) {
  const float* tracks = (const float*)d_in[0];
  const float* mp     = (const float*)d_in[1];
  float* ws  = (float*)d_ws;
  float* out = (float*)d_out;

  hipLaunchKernelGGL(k_setup,  dim3(1),    dim3(64),  0, stream, mp, ws);
  hipLaunchKernelGGL(k_matpow, dim3(64),   dim3(192), 0, stream, ws);
  hipLaunchKernelGGL(k_phase1, dim3(CCH),  dim3(64),  0, stream, tracks, ws);
  hipLaunchKernelGGL(k_scanz,  dim3(1),    dim3(64),  0, stream, ws);
  hipLaunchKernelGGL(k_phase3, dim3(CCH),  dim3(64),  0, stream, tracks, ws);
  hipLaunchKernelGGL(k_smooth, dim3(NTR),  dim3(256), 0, stream,
                     (const v4f*)(ws + OFF_CI), ws + OFF_COMP, ws + OFF_QB);
  hipLaunchKernelGGL(k_mix1,   dim3(NST2/4),  dim3(256), 0, stream, ws);
  hipLaunchKernelGGL(k_mix2,   dim3(S_LEN/64), dim3(256), 0, stream, ws, out);
}

// Round 11
// 955.640 us; speedup vs baseline: 2.1141x; 2.1141x over previous
//
#include <hip/hip_runtime.h>
#include <math.h>

// ---------------------------------------------------------------------------
// AdvancedMixConsole: 64 tracks x 131072 samples.
//   gain -> 6 biquads (chunk-parallel linear recurrence, 12-dim state)
//        -> compressor: parallel static gain; serial smoother as 16-sample
//           composed max-affine chain (17 slopes aa^j ar^(16-j)); one block
//           per track: wave0 = chain with RAW-ASM ds_read_b128 + counted
//           s_waitcnt lgkmcnt(N) pins (depth-3 slot pipeline — asm-produced,
//           asm-consumed values cannot be sunk or rematerialized);
//           waves1-3 = global->LDS producers (double-buffered chunks).
//        -> pan/mix (parallel, two-stage).
// ---------------------------------------------------------------------------

#define S_LEN 131072
#define NTR   64
#define CCH   256          // chunks (biquad phase)
#define LCH   512          // samples per chunk
#define SMW   16           // smoother window
#define NST2  8192         // 16-sample windows per track
#define WPC2  32           // windows per biquad chunk
#define SCH2  128          // k_smooth steps per LDS chunk
#define NCH2  (NST2/SCH2)  // 64 LDS chunks
#define RECQ  5            // float4s per step record (17 slopes + pad)

typedef float v2f __attribute__((ext_vector_type(2)));
typedef float v4f __attribute__((ext_vector_type(4)));

// ws offsets in floats (total ~79.3 MB)
#define OFF_Y    0ull              // [131072][64]      EQ output y, sample-major
#define OFF_CI   8388608ull        // [64][NST2][20]    composed intercepts I[0..16]+pad
#define OFF_TV   8388608ull        // [131072][64]      tv = y*gain (ALIASES CI)
#define OFF_QB   18874368ull       // [64][NST2]        boundary q per window (track-major)
#define OFF_W    19398656ull       // [64][2]           cos/sin pan weights
#define OFF_COEF 19398784ull       // [64][32]          biquad coeffs
#define OFF_COMP 19400832ull       // [64][64]          compressor consts + 17 slopes
#define OFF_A    19404928ull       // [64][144]         cascade transition matrix
#define OFF_M    19414144ull       // [64][144]         A^LCH
#define OFF_F    19423360ull       // [64][CCH][12]     zero-init chunk finals
#define OFF_Z    19619968ull       // [64][CCH][12]     chunk init states

// ---------------------------------------------------------------------------
__global__ __launch_bounds__(64) void k_setup(const float* __restrict__ mp,
                                              float* __restrict__ ws) {
  int n = threadIdx.x;
  if (n >= NTR) return;
  const float* p = mp + n * 26;
  auto dn = [&](int i, double lo, double hi) { return (double)p[i] * (hi - lo) + lo; };

  double gain_db = dn(0, -24.0, 24.0);
  double glin = pow(10.0, gain_db / 20.0);
  const double nyq = 21050.0;  // 44100//2 - 1000

  double fg[6] = {dn(1,-24,24), dn(4,-24,24), dn(7,-24,24), dn(10,-24,24), dn(13,-24,24), dn(16,-24,24)};
  double ff[6] = {dn(2,20,2000), dn(5,80,2000), dn(8,2000,8000), dn(11,8000,12000), dn(14,12000,nyq), dn(17,6000,nyq)};
  double fq[6] = {dn(3,0.1,5), dn(6,0.1,5), dn(9,0.1,5), dn(12,0.1,5), dn(15,0.1,5), dn(18,0.1,5)};

  double B0[6], B1[6], B2[6], A1[6], A2[6];
  for (int k = 0; k < 6; k++) {
    double A  = pow(10.0, fg[k] / 40.0);
    double w0 = 2.0 * M_PI * ff[k] / 44100.0;
    double cw = cos(w0), sw = sin(w0);
    double al = sw / (2.0 * fq[k]);
    double sA = sqrt(A);
    double b0, b1, b2, a0, a1, a2;
    if (k == 0) {           // low shelf
      b0 = A*((A+1)-(A-1)*cw + 2*sA*al);
      b1 = 2*A*((A-1)-(A+1)*cw);
      b2 = A*((A+1)-(A-1)*cw - 2*sA*al);
      a0 = (A+1)+(A-1)*cw + 2*sA*al;
      a1 = -2*((A-1)+(A+1)*cw);
      a2 = (A+1)+(A-1)*cw - 2*sA*al;
    } else if (k == 5) {    // high shelf
      b0 = A*((A+1)+(A-1)*cw + 2*sA*al);
      b1 = -2*A*((A-1)+(A+1)*cw);
      b2 = A*((A+1)+(A-1)*cw - 2*sA*al);
      a0 = (A+1)-(A-1)*cw + 2*sA*al;
      a1 = 2*((A-1)-(A+1)*cw);
      a2 = (A+1)-(A-1)*cw - 2*sA*al;
    } else {                // peak
      b0 = 1 + al*A; b1 = -2*cw; b2 = 1 - al*A;
      a0 = 1 + al/A; a1 = -2*cw; a2 = 1 - al/A;
    }
    B0[k] = b0/a0; B1[k] = b1/a0; B2[k] = b2/a0; A1[k] = a1/a0; A2[k] = a2/a0;
  }
  // fold input gain into stage-0 numerator
  B0[0] *= glin; B1[0] *= glin; B2[0] *= glin;

  float* cf = ws + OFF_COEF + n * 32;
  for (int k = 0; k < 6; k++) {
    cf[k*5+0] = (float)B0[k]; cf[k*5+1] = (float)B1[k]; cf[k*5+2] = (float)B2[k];
    cf[k*5+3] = (float)A1[k]; cf[k*5+4] = (float)A2[k];
  }

  // compressor + pan constants
  double T = dn(19,-60,0), R = dn(20,1,10), atk = dn(21,1,1000), rel = dn(22,1,1000);
  double Kn = dn(23,3,24), mk = dn(24,0,24);
  double a_a = exp(-1.0 / (44100.0 * atk * 0.001));
  double a_r = exp(-1.0 / (44100.0 * rel * 0.001));
  double s   = (a_a < a_r) ? 1.0 : -1.0;     // q = s*p makes the recurrence pure-max
  double kca = s * (1.0 - a_a), kcr = s * (1.0 - a_r);
  double invR = 1.0 / R;
  const double K10 = 0.16609640474436813;    // log2(10)/20
  double theta = (double)p[25] * (M_PI / 2.0);

  float* cm = ws + OFF_COMP + n * 64;
  cm[0] = (float)a_a;  cm[1] = (float)a_r;  cm[2] = (float)kca; cm[3] = (float)kcr;
  cm[4] = (float)T;    cm[5] = (float)(Kn * 0.5);
  cm[6] = (float)(1.0 - invR);
  cm[7] = (float)((1.0 - invR) / (2.0 * Kn));
  cm[8] = (float)(mk * K10);   cm[9] = (float)(s * K10);
  cm[10] = (float)cos(theta);  cm[11] = (float)sin(theta);
  // 17 composed slopes aa^j * ar^(16-j), j = 0..16
  for (int j = 0; j <= 16; j++)
    cm[16+j] = (float)(pow(a_a, (double)j) * pow(a_r, (double)(16-j)));

  float* wp = ws + OFF_W + n*2;
  wp[0] = (float)cos(theta); wp[1] = (float)sin(theta);

  // homogeneous (x=0) cascade transition matrix, state = [s1_1,s2_1,...,s1_6,s2_6]
  double Am[12][12], yv[12], ny[12];
  for (int r = 0; r < 12; r++) { yv[r] = 0; for (int c = 0; c < 12; c++) Am[r][c] = 0; }
  for (int k = 0; k < 6; k++) {
    for (int c = 0; c < 12; c++) ny[c] = B0[k] * yv[c];
    ny[2*k] += 1.0;                                  // y_k = b0*y_{k-1} + s1_k
    for (int c = 0; c < 12; c++) Am[2*k][c]   = B1[k]*yv[c] - A1[k]*ny[c];
    Am[2*k][2*k+1] += 1.0;                           // + s2_k
    for (int c = 0; c < 12; c++) Am[2*k+1][c] = B2[k]*yv[c] - A2[k]*ny[c];
    for (int c = 0; c < 12; c++) yv[c] = ny[c];
  }
  float* Aw = ws + OFF_A + n * 144;
  for (int r = 0; r < 12; r++)
    for (int c = 0; c < 12; c++) Aw[r*12+c] = (float)Am[r][c];
}

// ---------------------------------------------------------------------------
__global__ __launch_bounds__(192) void k_matpow(float* __restrict__ ws) {
  __shared__ float As[144];
  int n = blockIdx.x, t = threadIdx.x;
  int r = t / 12, c = t % 12;
  if (t < 144) As[t] = ws[OFF_A + (size_t)n*144 + t];
  __syncthreads();
  for (int it = 0; it < 9; ++it) {   // A^(2^9) = A^LCH (LCH=512)
    float acc = 0.f;
    if (t < 144) {
      #pragma unroll
      for (int k = 0; k < 12; k++) acc += As[r*12+k] * As[k*12+c];
    }
    __syncthreads();
    if (t < 144) As[t] = acc;
    __syncthreads();
  }
  if (t < 144) ws[OFF_M + (size_t)n*144 + t] = As[t];
}

// ---------------------------------------------------------------------------
__device__ __forceinline__ void load_coefs(const float* cf, float* b0, v2f* bb, v2f* naa) {
  #pragma unroll
  for (int k = 0; k < 6; k++) {
    b0[k]  = cf[k*5+0];
    bb[k]  = (v2f){cf[k*5+1], cf[k*5+2]};
    naa[k] = (v2f){-cf[k*5+3], -cf[k*5+4]};
  }
}

__device__ __forceinline__ float cascade_step(float x, float* b0, v2f* bb, v2f* naa, v2f* st) {
  #pragma unroll
  for (int k = 0; k < 6; k++) {
    float y  = fmaf(b0[k], x, st[k].x);
    v2f upd  = __builtin_elementwise_fma(bb[k], (v2f){x, x}, (v2f){st[k].y, 0.f});
    st[k]    = __builtin_elementwise_fma(naa[k], (v2f){y, y}, upd);
    x = y;
  }
  return x;
}

// phase 1: zero-init chunk finals
__global__ __launch_bounds__(64) void k_phase1(const float* __restrict__ tracks,
                                               float* __restrict__ ws) {
  int j = blockIdx.x, n = threadIdx.x;
  float b0[6]; v2f bb[6], naa[6];
  load_coefs(ws + OFF_COEF + n*32, b0, bb, naa);
  v2f st[6];
  #pragma unroll
  for (int k = 0; k < 6; k++) st[k] = (v2f){0.f, 0.f};
  const float4* xp = (const float4*)(tracks + (size_t)n*S_LEN + (size_t)j*LCH);
  for (int i4 = 0; i4 < LCH/4; ++i4) {
    float4 xq = xp[i4];
    float xs[4] = {xq.x, xq.y, xq.z, xq.w};
    #pragma unroll
    for (int u = 0; u < 4; u++) (void)cascade_step(xs[u], b0, bb, naa, st);
  }
  float* f = ws + OFF_F + (size_t)n*(CCH*12) + (size_t)j*12;
  #pragma unroll
  for (int k = 0; k < 6; k++) { f[2*k] = st[k].x; f[2*k+1] = st[k].y; }
}

// serial scan of chunk-boundary states: z_{j+1} = M z_j + f_j
__global__ __launch_bounds__(64) void k_scanz(float* __restrict__ ws) {
  int n = threadIdx.x;
  float M[144];
  #pragma unroll
  for (int i = 0; i < 144; i++) M[i] = ws[OFF_M + (size_t)n*144 + i];
  float z[12];
  #pragma unroll
  for (int r = 0; r < 12; r++) z[r] = 0.f;
  const float* fb = ws + OFF_F + (size_t)n*(CCH*12);
  float*       zb = ws + OFF_Z + (size_t)n*(CCH*12);
  for (int j = 0; j < CCH; j++) {
    #pragma unroll
    for (int r = 0; r < 12; r++) zb[j*12+r] = z[r];
    float nz[12];
    #pragma unroll
    for (int r = 0; r < 12; r++) {
      float acc = fb[j*12+r];
      #pragma unroll
      for (int c = 0; c < 12; c++) acc = fmaf(M[r*12+c], z[c], acc);
      nz[r] = acc;
    }
    #pragma unroll
    for (int r = 0; r < 12; r++) z[r] = nz[r];
  }
}

// phase 3: correct-init EQ; per-sample static gain; per-16-sample-window
// composed max-affine intercepts I[0..16] (I[j] = best path with j attacks),
// written as 80B records [track][step][20] for k_smooth's uniform loads.
__global__ __launch_bounds__(64) void k_phase3(const float* __restrict__ tracks,
                                               float* __restrict__ ws) {
  int j = blockIdx.x, n = threadIdx.x;
  float b0[6]; v2f bb[6], naa[6];
  load_coefs(ws + OFF_COEF + n*32, b0, bb, naa);
  const float* cm = ws + OFF_COMP + n*64;
  float a_a = cm[0], a_r = cm[1], kca = cm[2], kcr = cm[3];
  float T = cm[4], hK = cm[5], cg1 = cm[6], cg2 = cm[7];
  v2f st[6];
  const float* zp = ws + OFF_Z + (size_t)n*(CCH*12) + (size_t)j*12;
  #pragma unroll
  for (int k = 0; k < 6; k++) st[k] = (v2f){zp[2*k], zp[2*k+1]};

  const float4* xp = (const float4*)(tracks + (size_t)n*S_LEN + (size_t)j*LCH);
  float* yb = ws + OFF_Y + (size_t)j*LCH*64 + n;                      // [sample][track]
  float* cw = ws + OFF_CI + ((size_t)n*NST2 + (size_t)j*WPC2)*20;     // [track][step][20]

  for (int w = 0; w < WPC2; ++w) {
    float I[17];
    I[0] = 0.f;
    #pragma unroll
    for (int jj = 1; jj < 17; ++jj) I[jj] = -1e30f;
    #pragma unroll
    for (int i4 = 0; i4 < 4; ++i4) {
      float4 xq = xp[w*4 + i4];
      float xs[4] = {xq.x, xq.y, xq.z, xq.w};
      #pragma unroll
      for (int u = 0; u < 4; ++u) {
        const int i = i4*4 + u;
        float y = cascade_step(xs[u], b0, bb, naa, st);
        yb[(w*16 + i)*64] = y;
        float v   = fabsf(y) + 1e-8f;
        float xdb = 6.020599913279624f * __log2f(v);
        float d   = xdb - T;
        float dk  = d + hK;
        float gg  = (d > hK) ? (cg1*d) : (cg2*dk*dk);
        gg = (d < -hK) ? 0.f : gg;
        float ca = kca*gg, cr = kcr*gg;
        // compose one sample into the window map (descending j, in place)
        #pragma unroll
        for (int jj = 16; jj >= 0; --jj) {
          if (jj <= i+1) {
            float up = (jj > 0) ? fmaf(a_a, I[jj-1], ca) : -1e30f;
            I[jj] = fmaxf(up, fmaf(a_r, I[jj], cr));
          }
        }
      }
    }
    float4* cq = (float4*)(cw + (size_t)w*20);
    cq[0] = make_float4(I[0],  I[1],  I[2],  I[3]);
    cq[1] = make_float4(I[4],  I[5],  I[6],  I[7]);
    cq[2] = make_float4(I[8],  I[9],  I[10], I[11]);
    cq[3] = make_float4(I[12], I[13], I[14], I[15]);
    cq[4] = make_float4(I[16], 0.f, 0.f, 0.f);
  }
}

// ---------------------------------------------------------------------------
// serial max-affine smoother. One 256-thread block per track:
//   wave 0: depth-3 slot pipeline. Loads are raw-asm ds_read_b128 (5/step);
//     each step opens with asm s_waitcnt lgkmcnt(10) carrying the slot regs
//     as "+v" — waits exactly for that slot, keeps 2 slots (10 ds ops) in
//     flight. Asm-def -> asm-use values are pinned in VGPRs; the scheduler
//     cannot sink or rematerialize them (the R5-R10 failure mode).
//   waves 1-3: global->LDS producers, double-buffered chunks (as R8).
// q is wave-uniform; every step all lanes store it to qb[track][step]
// (same-address store collapses in HW) — no lane-capture needed.

#define CHAIN_REFILL(s0,s1,s2,s3,s4, ADDR)                                   \
  asm volatile("ds_read_b128 %0, %5 offset:0\n\t"                            \
               "ds_read_b128 %1, %5 offset:16\n\t"                           \
               "ds_read_b128 %2, %5 offset:32\n\t"                           \
               "ds_read_b128 %3, %5 offset:48\n\t"                           \
               "ds_read_b128 %4, %5 offset:64"                               \
               : "=v"(s0), "=v"(s1), "=v"(s2), "=v"(s3), "=v"(s4)            \
               : "v"(ADDR));

#define CHAIN_WAIT(s0,s1,s2,s3,s4, CNT)                                      \
  asm volatile("s_waitcnt lgkmcnt(" #CNT ")"                                 \
               : "+v"(s0), "+v"(s1), "+v"(s2), "+v"(s3), "+v"(s4));

#define EVAL17(A,B,C,D,E)                                                    \
  {                                                                          \
    float t0  = fmaf(S0,q,A.x),  t1  = fmaf(S1,q,A.y);                       \
    float t2  = fmaf(S2,q,A.z),  t3  = fmaf(S3,q,A.w);                       \
    float t4  = fmaf(S4,q,B.x),  t5  = fmaf(S5,q,B.y);                       \
    float t6  = fmaf(S6,q,B.z),  t7  = fmaf(S7,q,B.w);                       \
    float t8  = fmaf(S8,q,C.x),  t9  = fmaf(S9,q,C.y);                       \
    float t10 = fmaf(S10,q,C.z), t11 = fmaf(S11,q,C.w);                      \
    float t12 = fmaf(S12,q,D.x), t13 = fmaf(S13,q,D.y);                      \
    float t14 = fmaf(S14,q,D.z), t15 = fmaf(S15,q,D.w);                      \
    float t16 = fmaf(S16,q,E.x);                                             \
    float m0 = fmaxf(fmaxf(t0,t1),t2);                                       \
    float m1 = fmaxf(fmaxf(t3,t4),t5);                                       \
    float m2 = fmaxf(fmaxf(t6,t7),t8);                                       \
    float m3 = fmaxf(fmaxf(t9,t10),t11);                                     \
    float m4 = fmaxf(fmaxf(t12,t13),t14);                                    \
    float m5 = fmaxf(fmaxf(t15,t16),m0);                                     \
    float mm = fmaxf(fmaxf(m1,m2),m3);                                       \
    q = fmaxf(fmaxf(m4,m5),mm);                                              \
  }

__global__ __launch_bounds__(256, 1) void k_smooth(const v4f* __restrict__ cp,
                                                   const float* __restrict__ cmv,
                                                   float* __restrict__ qb) {
  __shared__ v4f buf[2][SCH2*RECQ];         // 2 x 10KB
  const int n = blockIdx.x;
  const int tid = threadIdx.x;
  const int wave = tid >> 6;
  const v4f* __restrict__ base = cp + (size_t)n * NST2 * RECQ;

  // preload chunk 0 (all threads)
  for (int i = tid; i < SCH2*RECQ; i += 256) buf[0][i] = base[i];
  __syncthreads();

  const float* cm = cmv + n*64;
  const float S0  = cm[16], S1  = cm[17], S2  = cm[18], S3  = cm[19];
  const float S4  = cm[20], S5  = cm[21], S6  = cm[22], S7  = cm[23];
  const float S8  = cm[24], S9  = cm[25], S10 = cm[26], S11 = cm[27];
  const float S12 = cm[28], S13 = cm[29], S14 = cm[30], S15 = cm[31];
  const float S16 = cm[32];

  float q = 0.f;
  float* qt = qb + (size_t)n * NST2;        // [track][step]

  for (int c2 = 0; c2 < NCH2; ++c2) {
    if (wave != 0) {
      if (c2 + 1 < NCH2) {
        const v4f* src = base + (size_t)(c2+1)*SCH2*RECQ;
        v4f* dst = &buf[(c2+1) & 1][0];
        for (int i = tid - 64; i < SCH2*RECQ; i += 192) dst[i] = src[i];
      }
    } else {
      // low 32 bits of the flat shared address = LDS byte offset (gfx9
      // shared aperture is 4GB-aligned; generic->AS(3) lowering truncates).
      const unsigned base3 = (unsigned)(unsigned long long)(const void*)&buf[c2 & 1][0];
      float* qp = qt + (size_t)c2 * SCH2;
      v4f A0,A1,A2,A3,A4, B0,B1,B2,B3,B4, C0,C1,C2,C3,C4;
      CHAIN_REFILL(A0,A1,A2,A3,A4, base3 + 0u*80u)
      CHAIN_REFILL(B0,B1,B2,B3,B4, base3 + 1u*80u)
      CHAIN_REFILL(C0,C1,C2,C3,C4, base3 + 2u*80u)
      int t = 0;
      for (int it = 0; it < 41; ++it) {     // 41*3 = 123 steps with refill
        CHAIN_WAIT(A0,A1,A2,A3,A4, 10)
        EVAL17(A0,A1,A2,A3,A4)  qp[t+0] = q;
        CHAIN_REFILL(A0,A1,A2,A3,A4, base3 + (unsigned)(t+3)*80u)
        CHAIN_WAIT(B0,B1,B2,B3,B4, 10)
        EVAL17(B0,B1,B2,B3,B4)  qp[t+1] = q;
        CHAIN_REFILL(B0,B1,B2,B3,B4, base3 + (unsigned)(t+4)*80u)
        CHAIN_WAIT(C0,C1,C2,C3,C4, 10)
        EVAL17(C0,C1,C2,C3,C4)  qp[t+2] = q;
        CHAIN_REFILL(C0,C1,C2,C3,C4, base3 + (unsigned)(t+5)*80u)
        t += 3;
      }
      // t = 123: steps 123..127 (refill 126,127 only)
      CHAIN_WAIT(A0,A1,A2,A3,A4, 10)
      EVAL17(A0,A1,A2,A3,A4)  qp[123] = q;
      CHAIN_REFILL(A0,A1,A2,A3,A4, base3 + 126u*80u)
      CHAIN_WAIT(B0,B1,B2,B3,B4, 10)
      EVAL17(B0,B1,B2,B3,B4)  qp[124] = q;
      CHAIN_REFILL(B0,B1,B2,B3,B4, base3 + 127u*80u)
      CHAIN_WAIT(C0,C1,C2,C3,C4, 10)
      EVAL17(C0,C1,C2,C3,C4)  qp[125] = q;
      CHAIN_WAIT(A0,A1,A2,A3,A4, 5)
      EVAL17(A0,A1,A2,A3,A4)  qp[126] = q;
      CHAIN_WAIT(B0,B1,B2,B3,B4, 0)
      EVAL17(B0,B1,B2,B3,B4)  qp[127] = q;
    }
    __syncthreads();
  }
}

// tv = y * 10^((mk - p)/20): exact 16-step reconstruction from boundary q.
// lanes = tracks -> fully coalesced y/tv rows.
__global__ __launch_bounds__(256) void k_mix1(float* __restrict__ ws) {
  const int n  = threadIdx.x & 63;
  const int kk = blockIdx.x*4 + (threadIdx.x >> 6);
  const float* cm = ws + OFF_COMP + n*64;
  const float aa = cm[0], ar = cm[1], kca = cm[2], kcr = cm[3];
  const float T = cm[4], hK = cm[5], cg1 = cm[6], cg2 = cm[7];
  const float mkK = cm[8], sK = cm[9];
  const float* __restrict__ yb  = ws + OFF_Y;
  float* __restrict__       tvb = ws + OFF_TV;
  float q = (kk > 0) ? ws[OFF_QB + (size_t)n*NST2 + (kk-1)] : 0.f;
  #pragma unroll
  for (int i = 0; i < SMW; ++i) {
    float y = yb[(size_t)(kk*SMW + i)*64 + n];
    float v   = fabsf(y) + 1e-8f;
    float xdb = 6.020599913279624f * __log2f(v);
    float d   = xdb - T;
    float dk  = d + hK;
    float gg  = (d > hK) ? (cg1*d) : (cg2*dk*dk);
    gg = (d < -hK) ? 0.f : gg;
    q = fmaxf(fmaf(aa, q, kca*gg), fmaf(ar, q, kcr*gg));
    float sc = exp2f(fmaf(-sK, q, mkK));
    tvb[(size_t)(kk*SMW + i)*64 + n] = y * sc;
  }
}

// 16-track pan reduction -> out[b][2][S]
__global__ __launch_bounds__(256) void k_mix2(const float* __restrict__ ws,
                                              float* __restrict__ out) {
  const int b = threadIdx.x & 3;
  const int s = blockIdx.x*64 + (threadIdx.x >> 2);
  const float* __restrict__ tvb = ws + OFF_TV;
  const float2* __restrict__ wp = (const float2*)(ws + OFF_W);
  float accL = 0.f, accR = 0.f;
  const int n0 = b*16;
  #pragma unroll
  for (int t = 0; t < 16; ++t) {
    float tv = tvb[(size_t)s*64 + n0 + t];
    float2 w2 = wp[n0 + t];
    accL = fmaf(w2.x, tv, accL);
    accR = fmaf(w2.y, tv, accR);
  }
  out[(size_t)(b*2 + 0)*S_LEN + s] = accL;
  out[(size_t)(b*2 + 1)*S_LEN + s] = accR;
}

// ---------------------------------------------------------------------------
extern "C" void kernel_launch(void* const* d_in, const int* in_sizes, int n_in,
                              void* d_out, int out_size, void* d_ws, size_t ws_size,
                              hipStream_t stream) {
  const float* tracks = (const float*)d_in[0];
  const float* mp     = (const float*)d_in[1];
  float* ws  = (float*)d_ws;
  float* out = (float*)d_out;

  hipLaunchKernelGGL(k_setup,  dim3(1),    dim3(64),  0, stream, mp, ws);
  hipLaunchKernelGGL(k_matpow, dim3(64),   dim3(192), 0, stream, ws);
  hipLaunchKernelGGL(k_phase1, dim3(CCH),  dim3(64),  0, stream, tracks, ws);
  hipLaunchKernelGGL(k_scanz,  dim3(1),    dim3(64),  0, stream, ws);
  hipLaunchKernelGGL(k_phase3, dim3(CCH),  dim3(64),  0, stream, tracks, ws);
  hipLaunchKernelGGL(k_smooth, dim3(NTR),  dim3(256), 0, stream,
                     (const v4f*)(ws + OFF_CI), ws + OFF_COMP, ws + OFF_QB);
  hipLaunchKernelGGL(k_mix1,   dim3(NST2/4),  dim3(256), 0, stream, ws);
  hipLaunchKernelGGL(k_mix2,   dim3(S_LEN/64), dim3(256), 0, stream, ws, out);
}

// Round 13
// 636.118 us; speedup vs baseline: 3.1760x; 1.5023x over previous
//
#include <hip/hip_runtime.h>
#include <math.h>

// ---------------------------------------------------------------------------
// AdvancedMixConsole: 64 tracks x 131072 samples.
//   gain -> 6 biquads (chunk-parallel linear recurrence, 12-dim state)
//        -> compressor: parallel static gain; serial smoother as 64-sample
//           composed max-affine chain (65 slopes aa^j ar^(64-j)) evaluated
//           LANE-PARALLEL: lane j owns slope j, loads 1 float/step, 6-stage
//           DPP max-reduce + readlane -> SGPR q. No deep pipeline needed —
//           the R5-R11 failure mode (compiler refusing register pipelines)
//           is designed out. waves1-3 = global->LDS producers.
//        -> pan/mix (parallel, two-stage).
// ---------------------------------------------------------------------------

#define S_LEN 131072
#define NTR   64
#define CCH   256          // chunks (biquad phase)
#define LCH   512          // samples per chunk
#define SMW   64           // smoother window
#define NST3  2048         // 64-sample windows per track
#define WPC3  8            // windows per biquad chunk
#define RECF  68           // floats per step record (65 slopes + 3 pad)
#define SCH3  128          // k_smooth steps per LDS chunk
#define NCH3  16           // LDS chunks (2048/128)

typedef float v2f __attribute__((ext_vector_type(2)));

// ws offsets in floats (total ~71.4 MB)
#define OFF_Y    0ull              // [131072][64]      EQ output y, sample-major
#define OFF_CI   8388608ull        // [64][2048][68]    composed intercepts I[0..64]+pad (+1024 pad)
#define OFF_TV   8388608ull        // [131072][64]      tv (ALIASES CI; used after k_smooth)
#define OFF_QB   17302528ull       // [64][2048]        boundary q per window
#define OFF_W    17433600ull       // [64][2]           cos/sin pan weights
#define OFF_COEF 17433728ull       // [64][32]          biquad coeffs
#define OFF_COMP 17435776ull       // [64][128]         compressor consts + 65 slopes
#define OFF_A    17443968ull       // [64][144]         cascade transition matrix
#define OFF_M    17453184ull       // [64][144]         A^LCH
#define OFF_F    17462400ull       // [64][CCH][12]     zero-init chunk finals
#define OFF_Z    17659008ull       // [64][CCH][12]     chunk init states

// ---------------------------------------------------------------------------
__global__ __launch_bounds__(64) void k_setup(const float* __restrict__ mp,
                                              float* __restrict__ ws) {
  int n = threadIdx.x;
  if (n >= NTR) return;
  const float* p = mp + n * 26;
  auto dn = [&](int i, double lo, double hi) { return (double)p[i] * (hi - lo) + lo; };

  double gain_db = dn(0, -24.0, 24.0);
  double glin = pow(10.0, gain_db / 20.0);
  const double nyq = 21050.0;  // 44100//2 - 1000

  double fg[6] = {dn(1,-24,24), dn(4,-24,24), dn(7,-24,24), dn(10,-24,24), dn(13,-24,24), dn(16,-24,24)};
  double ff[6] = {dn(2,20,2000), dn(5,80,2000), dn(8,2000,8000), dn(11,8000,12000), dn(14,12000,nyq), dn(17,6000,nyq)};
  double fq[6] = {dn(3,0.1,5), dn(6,0.1,5), dn(9,0.1,5), dn(12,0.1,5), dn(15,0.1,5), dn(18,0.1,5)};

  double B0[6], B1[6], B2[6], A1[6], A2[6];
  for (int k = 0; k < 6; k++) {
    double A  = pow(10.0, fg[k] / 40.0);
    double w0 = 2.0 * M_PI * ff[k] / 44100.0;
    double cw = cos(w0), sw = sin(w0);
    double al = sw / (2.0 * fq[k]);
    double sA = sqrt(A);
    double b0, b1, b2, a0, a1, a2;
    if (k == 0) {           // low shelf
      b0 = A*((A+1)-(A-1)*cw + 2*sA*al);
      b1 = 2*A*((A-1)-(A+1)*cw);
      b2 = A*((A+1)-(A-1)*cw - 2*sA*al);
      a0 = (A+1)+(A-1)*cw + 2*sA*al;
      a1 = -2*((A-1)+(A+1)*cw);
      a2 = (A+1)+(A-1)*cw - 2*sA*al;
    } else if (k == 5) {    // high shelf
      b0 = A*((A+1)+(A-1)*cw + 2*sA*al);
      b1 = -2*A*((A-1)+(A+1)*cw);
      b2 = A*((A+1)+(A-1)*cw - 2*sA*al);
      a0 = (A+1)-(A-1)*cw + 2*sA*al;
      a1 = 2*((A-1)-(A+1)*cw);
      a2 = (A+1)-(A-1)*cw - 2*sA*al;
    } else {                // peak
      b0 = 1 + al*A; b1 = -2*cw; b2 = 1 - al*A;
      a0 = 1 + al/A; a1 = -2*cw; a2 = 1 - al/A;
    }
    B0[k] = b0/a0; B1[k] = b1/a0; B2[k] = b2/a0; A1[k] = a1/a0; A2[k] = a2/a0;
  }
  // fold input gain into stage-0 numerator
  B0[0] *= glin; B1[0] *= glin; B2[0] *= glin;

  float* cf = ws + OFF_COEF + n * 32;
  for (int k = 0; k < 6; k++) {
    cf[k*5+0] = (float)B0[k]; cf[k*5+1] = (float)B1[k]; cf[k*5+2] = (float)B2[k];
    cf[k*5+3] = (float)A1[k]; cf[k*5+4] = (float)A2[k];
  }

  // compressor + pan constants
  double T = dn(19,-60,0), R = dn(20,1,10), atk = dn(21,1,1000), rel = dn(22,1,1000);
  double Kn = dn(23,3,24), mk = dn(24,0,24);
  double a_a = exp(-1.0 / (44100.0 * atk * 0.001));
  double a_r = exp(-1.0 / (44100.0 * rel * 0.001));
  double s   = (a_a < a_r) ? 1.0 : -1.0;     // q = s*p makes the recurrence pure-max
  double kca = s * (1.0 - a_a), kcr = s * (1.0 - a_r);
  double invR = 1.0 / R;
  const double K10 = 0.16609640474436813;    // log2(10)/20
  double theta = (double)p[25] * (M_PI / 2.0);

  float* cm = ws + OFF_COMP + n * 128;
  cm[0] = (float)a_a;  cm[1] = (float)a_r;  cm[2] = (float)kca; cm[3] = (float)kcr;
  cm[4] = (float)T;    cm[5] = (float)(Kn * 0.5);
  cm[6] = (float)(1.0 - invR);
  cm[7] = (float)((1.0 - invR) / (2.0 * Kn));
  cm[8] = (float)(mk * K10);   cm[9] = (float)(s * K10);
  cm[10] = (float)cos(theta);  cm[11] = (float)sin(theta);
  // 65 composed slopes aa^j * ar^(64-j), j = 0..64
  for (int j = 0; j <= 64; j++)
    cm[16+j] = (float)(pow(a_a, (double)j) * pow(a_r, (double)(64-j)));

  float* wp = ws + OFF_W + n*2;
  wp[0] = (float)cos(theta); wp[1] = (float)sin(theta);

  // homogeneous (x=0) cascade transition matrix, state = [s1_1,s2_1,...,s1_6,s2_6]
  double Am[12][12], yv[12], ny[12];
  for (int r = 0; r < 12; r++) { yv[r] = 0; for (int c = 0; c < 12; c++) Am[r][c] = 0; }
  for (int k = 0; k < 6; k++) {
    for (int c = 0; c < 12; c++) ny[c] = B0[k] * yv[c];
    ny[2*k] += 1.0;                                  // y_k = b0*y_{k-1} + s1_k
    for (int c = 0; c < 12; c++) Am[2*k][c]   = B1[k]*yv[c] - A1[k]*ny[c];
    Am[2*k][2*k+1] += 1.0;                           // + s2_k
    for (int c = 0; c < 12; c++) Am[2*k+1][c] = B2[k]*yv[c] - A2[k]*ny[c];
    for (int c = 0; c < 12; c++) yv[c] = ny[c];
  }
  float* Aw = ws + OFF_A + n * 144;
  for (int r = 0; r < 12; r++)
    for (int c = 0; c < 12; c++) Aw[r*12+c] = (float)Am[r][c];
}

// ---------------------------------------------------------------------------
__global__ __launch_bounds__(192) void k_matpow(float* __restrict__ ws) {
  __shared__ float As[144];
  int n = blockIdx.x, t = threadIdx.x;
  int r = t / 12, c = t % 12;
  if (t < 144) As[t] = ws[OFF_A + (size_t)n*144 + t];
  __syncthreads();
  for (int it = 0; it < 9; ++it) {   // A^(2^9) = A^LCH (LCH=512)
    float acc = 0.f;
    if (t < 144) {
      #pragma unroll
      for (int k = 0; k < 12; k++) acc += As[r*12+k] * As[k*12+c];
    }
    __syncthreads();
    if (t < 144) As[t] = acc;
    __syncthreads();
  }
  if (t < 144) ws[OFF_M + (size_t)n*144 + t] = As[t];
}

// ---------------------------------------------------------------------------
__device__ __forceinline__ void load_coefs(const float* cf, float* b0, v2f* bb, v2f* naa) {
  #pragma unroll
  for (int k = 0; k < 6; k++) {
    b0[k]  = cf[k*5+0];
    bb[k]  = (v2f){cf[k*5+1], cf[k*5+2]};
    naa[k] = (v2f){-cf[k*5+3], -cf[k*5+4]};
  }
}

__device__ __forceinline__ float cascade_step(float x, float* b0, v2f* bb, v2f* naa, v2f* st) {
  #pragma unroll
  for (int k = 0; k < 6; k++) {
    float y  = fmaf(b0[k], x, st[k].x);
    v2f upd  = __builtin_elementwise_fma(bb[k], (v2f){x, x}, (v2f){st[k].y, 0.f});
    st[k]    = __builtin_elementwise_fma(naa[k], (v2f){y, y}, upd);
    x = y;
  }
  return x;
}

// phase 1: zero-init chunk finals
__global__ __launch_bounds__(64) void k_phase1(const float* __restrict__ tracks,
                                               float* __restrict__ ws) {
  int j = blockIdx.x, n = threadIdx.x;
  float b0[6]; v2f bb[6], naa[6];
  load_coefs(ws + OFF_COEF + n*32, b0, bb, naa);
  v2f st[6];
  #pragma unroll
  for (int k = 0; k < 6; k++) st[k] = (v2f){0.f, 0.f};
  const float4* xp = (const float4*)(tracks + (size_t)n*S_LEN + (size_t)j*LCH);
  for (int i4 = 0; i4 < LCH/4; ++i4) {
    float4 xq = xp[i4];
    float xs[4] = {xq.x, xq.y, xq.z, xq.w};
    #pragma unroll
    for (int u = 0; u < 4; u++) (void)cascade_step(xs[u], b0, bb, naa, st);
  }
  float* f = ws + OFF_F + (size_t)n*(CCH*12) + (size_t)j*12;
  #pragma unroll
  for (int k = 0; k < 6; k++) { f[2*k] = st[k].x; f[2*k+1] = st[k].y; }
}

// serial scan of chunk-boundary states: z_{j+1} = M z_j + f_j
__global__ __launch_bounds__(64) void k_scanz(float* __restrict__ ws) {
  int n = threadIdx.x;
  float M[144];
  #pragma unroll
  for (int i = 0; i < 144; i++) M[i] = ws[OFF_M + (size_t)n*144 + i];
  float z[12];
  #pragma unroll
  for (int r = 0; r < 12; r++) z[r] = 0.f;
  const float* fb = ws + OFF_F + (size_t)n*(CCH*12);
  float*       zb = ws + OFF_Z + (size_t)n*(CCH*12);
  for (int j = 0; j < CCH; j++) {
    #pragma unroll
    for (int r = 0; r < 12; r++) zb[j*12+r] = z[r];
    float nz[12];
    #pragma unroll
    for (int r = 0; r < 12; r++) {
      float acc = fb[j*12+r];
      #pragma unroll
      for (int c = 0; c < 12; c++) acc = fmaf(M[r*12+c], z[c], acc);
      nz[r] = acc;
    }
    #pragma unroll
    for (int r = 0; r < 12; r++) z[r] = nz[r];
  }
}

// phase 3: correct-init EQ; per-sample static gain; per-64-sample-window
// composed max-affine intercepts I[0..64] (I[j] = best path with j attacks),
// written as 272B records [track][step][68] for k_smooth's coalesced loads.
__global__ __launch_bounds__(64, 1) void k_phase3(const float* __restrict__ tracks,
                                                  float* __restrict__ ws) {
  int j = blockIdx.x, n = threadIdx.x;
  float b0[6]; v2f bb[6], naa[6];
  load_coefs(ws + OFF_COEF + n*32, b0, bb, naa);
  const float* cm = ws + OFF_COMP + n*128;
  float a_a = cm[0], a_r = cm[1], kca = cm[2], kcr = cm[3];
  float T = cm[4], hK = cm[5], cg1 = cm[6], cg2 = cm[7];
  v2f st[6];
  const float* zp = ws + OFF_Z + (size_t)n*(CCH*12) + (size_t)j*12;
  #pragma unroll
  for (int k = 0; k < 6; k++) st[k] = (v2f){zp[2*k], zp[2*k+1]};

  const float4* xp = (const float4*)(tracks + (size_t)n*S_LEN + (size_t)j*LCH);
  float* yb = ws + OFF_Y + (size_t)j*LCH*64 + n;                        // [sample][track]
  float* cw = ws + OFF_CI + (size_t)n*(NST3*RECF) + (size_t)j*WPC3*RECF;

  for (int w = 0; w < WPC3; ++w) {
    float I[65];
    I[0] = 0.f;
    #pragma unroll
    for (int jj = 1; jj < 65; ++jj) I[jj] = -1e30f;
    #pragma unroll
    for (int i4 = 0; i4 < 16; ++i4) {
      float4 xq = xp[w*16 + i4];
      float xs[4] = {xq.x, xq.y, xq.z, xq.w};
      #pragma unroll
      for (int u = 0; u < 4; ++u) {
        const int i = i4*4 + u;
        float y = cascade_step(xs[u], b0, bb, naa, st);
        yb[(w*64 + i)*64] = y;
        float v   = fabsf(y) + 1e-8f;
        float xdb = 6.020599913279624f * __log2f(v);
        float d   = xdb - T;
        float dk  = d + hK;
        float gg  = (d > hK) ? (cg1*d) : (cg2*dk*dk);
        gg = (d < -hK) ? 0.f : gg;
        float ca = kca*gg, cr = kcr*gg;
        // compose one sample into the window map (descending j, in place)
        #pragma unroll
        for (int jj = 64; jj >= 0; --jj) {
          if (jj <= i+1) {
            float up = (jj > 0) ? fmaf(a_a, I[jj-1], ca) : -1e30f;
            I[jj] = fmaxf(up, fmaf(a_r, I[jj], cr));
          }
        }
      }
    }
    float4* cq = (float4*)(cw + (size_t)w*RECF);
    #pragma unroll
    for (int r = 0; r < 16; ++r)
      cq[r] = make_float4(I[4*r], I[4*r+1], I[4*r+2], I[4*r+3]);
    (cw + (size_t)w*RECF)[64] = I[64];
    (cw + (size_t)w*RECF)[65] = 0.f;
    (cw + (size_t)w*RECF)[66] = 0.f;
    (cw + (size_t)w*RECF)[67] = 0.f;
  }
}

// ---------------------------------------------------------------------------
// serial max-affine smoother, LANE-PARALLEL terms. One 256-thread block/track:
//   wave 0: lane j owns slope S_j (register). Per step: load I[step][lane]
//     (1 coalesced ds_read_b32) + uniform I[step][64]; t = fma(S,q,I);
//     include term 64 in every lane (max is idempotent — duplicate harmless);
//     6-stage DPP max-reduce (row_shr 1/2/4/8, bcast15, bcast31) -> lane 63;
//     readlane -> SGPR q. Dep chain ~40 cyc, only 2 scalar floats of
//     prefetch state (4-deep rotation) — nothing for the compiler to spill.
//   waves 1-3: global->LDS producers, double-buffered 34.8KB chunks.
__device__ __forceinline__ float dpp_max(float x, const int ctrl) {
  int xi = __float_as_int(x);
  int yi;
  switch (ctrl) {   // ctrl must be a literal for the builtin
    case 0x111: yi = __builtin_amdgcn_update_dpp(xi, xi, 0x111, 0xf, 0xf, false); break;
    case 0x112: yi = __builtin_amdgcn_update_dpp(xi, xi, 0x112, 0xf, 0xf, false); break;
    case 0x114: yi = __builtin_amdgcn_update_dpp(xi, xi, 0x114, 0xf, 0xf, false); break;
    case 0x118: yi = __builtin_amdgcn_update_dpp(xi, xi, 0x118, 0xf, 0xf, false); break;
    case 0x142: yi = __builtin_amdgcn_update_dpp(xi, xi, 0x142, 0xf, 0xf, false); break;
    default:    yi = __builtin_amdgcn_update_dpp(xi, xi, 0x143, 0xf, 0xf, false); break;
  }
  return fmaxf(x, __int_as_float(yi));
}

#define KSTEP(IV, UV, SIDX)                                                  \
  {                                                                          \
    float t = fmaf(Sv, qs, IV);                                              \
    float t64 = fmaf(S64v, qs, UV);                                          \
    t = fmaxf(t, t64);                                                       \
    t = dpp_max(t, 0x111);                                                   \
    t = dpp_max(t, 0x112);                                                   \
    t = dpp_max(t, 0x114);                                                   \
    t = dpp_max(t, 0x118);                                                   \
    t = dpp_max(t, 0x142);                                                   \
    t = dpp_max(t, 0x143);                                                   \
    qs = __int_as_float(__builtin_amdgcn_readlane(__float_as_int(t), 63));   \
    qtc[SIDX] = qs;                                                          \
  }

__global__ __launch_bounds__(256, 1) void k_smooth(float* __restrict__ ws) {
  __shared__ float buf[2][SCH3*RECF];       // 2 x 34816 B
  const int n = blockIdx.x;
  const int tid = threadIdx.x;
  const int wave = tid >> 6, l = tid & 63;
  const float4* __restrict__ base4 =
      (const float4*)(ws + OFF_CI) + (size_t)n*(NST3*RECF/4);

  // preload chunk 0 (all threads)
  {
    const float4* s4 = base4;
    float4* d4 = (float4*)&buf[0][0];
    for (int i = tid; i < SCH3*RECF/4; i += 256) d4[i] = s4[i];
  }
  __syncthreads();

  const float* cm = ws + OFF_COMP + n*128;
  const float Sv   = cm[16 + l];    // lane j owns slope j
  const float S64v = cm[16 + 64];
  float qs = 0.f;
  float* qt = ws + OFF_QB + (size_t)n * NST3;

  for (int c2 = 0; c2 < NCH3; ++c2) {
    if (wave != 0) {
      if (c2 + 1 < NCH3) {
        const float4* src = base4 + (size_t)(c2+1)*(SCH3*RECF/4);
        float4* dst = (float4*)&buf[(c2+1) & 1][0];
        const int p = tid - 64;               // 0..191
        #pragma unroll
        for (int r = 0; r < 3; ++r) {
          int i0 = p + r*768;
          float4 a = src[i0];                 // loads unguarded (global pad)
          float4 b = src[i0 + 192];
          float4 cc = src[i0 + 384];
          float4 d = src[i0 + 576];
          if (i0       < SCH3*RECF/4) dst[i0]       = a;
          if (i0 + 192 < SCH3*RECF/4) dst[i0 + 192] = b;
          if (i0 + 384 < SCH3*RECF/4) dst[i0 + 384] = cc;
          if (i0 + 576 < SCH3*RECF/4) dst[i0 + 576] = d;
        }
      }
    } else {
      const float* Lb = &buf[c2 & 1][0];
      float* qtc = qt + c2*SCH3;
      // 4-deep rotation of prefetched scalars
      float i0v = Lb[0*RECF + l], u0 = Lb[0*RECF + 64];
      float i1v = Lb[1*RECF + l], u1 = Lb[1*RECF + 64];
      float i2v = Lb[2*RECF + l], u2 = Lb[2*RECF + 64];
      float i3v = Lb[3*RECF + l], u3 = Lb[3*RECF + 64];
      for (int s = 0; s < SCH3 - 4; s += 4) {
        KSTEP(i0v, u0, s+0)  i0v = Lb[(s+4)*RECF + l]; u0 = Lb[(s+4)*RECF + 64];
        KSTEP(i1v, u1, s+1)  i1v = Lb[(s+5)*RECF + l]; u1 = Lb[(s+5)*RECF + 64];
        KSTEP(i2v, u2, s+2)  i2v = Lb[(s+6)*RECF + l]; u2 = Lb[(s+6)*RECF + 64];
        KSTEP(i3v, u3, s+3)  i3v = Lb[(s+7)*RECF + l]; u3 = Lb[(s+7)*RECF + 64];
      }
      {
        const int s = SCH3 - 4;
        KSTEP(i0v, u0, s+0)
        KSTEP(i1v, u1, s+1)
        KSTEP(i2v, u2, s+2)
        KSTEP(i3v, u3, s+3)
      }
    }
    __syncthreads();
  }
}

// tv = y * 10^((mk - p)/20): exact 64-step reconstruction from boundary q.
// lanes = tracks -> fully coalesced y/tv rows.
__global__ __launch_bounds__(256) void k_mix1(float* __restrict__ ws) {
  const int n  = threadIdx.x & 63;
  const int kk = blockIdx.x*4 + (threadIdx.x >> 6);
  const float* cm = ws + OFF_COMP + n*128;
  const float aa = cm[0], ar = cm[1], kca = cm[2], kcr = cm[3];
  const float T = cm[4], hK = cm[5], cg1 = cm[6], cg2 = cm[7];
  const float mkK = cm[8], sK = cm[9];
  const float* __restrict__ yb  = ws + OFF_Y;
  float* __restrict__       tvb = ws + OFF_TV;
  float q = (kk > 0) ? ws[OFF_QB + (size_t)n*NST3 + (kk-1)] : 0.f;
  #pragma unroll 8
  for (int i = 0; i < SMW; ++i) {
    float y = yb[(size_t)(kk*SMW + i)*64 + n];
    float v   = fabsf(y) + 1e-8f;
    float xdb = 6.020599913279624f * __log2f(v);
    float d   = xdb - T;
    float dk  = d + hK;
    float gg  = (d > hK) ? (cg1*d) : (cg2*dk*dk);
    gg = (d < -hK) ? 0.f : gg;
    q = fmaxf(fmaf(aa, q, kca*gg), fmaf(ar, q, kcr*gg));
    float sc = exp2f(fmaf(-sK, q, mkK));
    tvb[(size_t)(kk*SMW + i)*64 + n] = y * sc;
  }
}

// 16-track pan reduction -> out[b][2][S]
__global__ __launch_bounds__(256) void k_mix2(const float* __restrict__ ws,
                                              float* __restrict__ out) {
  const int b = threadIdx.x & 3;
  const int s = blockIdx.x*64 + (threadIdx.x >> 2);
  const float* __restrict__ tvb = ws + OFF_TV;
  const float2* __restrict__ wp = (const float2*)(ws + OFF_W);
  float accL = 0.f, accR = 0.f;
  const int n0 = b*16;
  #pragma unroll
  for (int t = 0; t < 16; ++t) {
    float tv = tvb[(size_t)s*64 + n0 + t];
    float2 w2 = wp[n0 + t];
    accL = fmaf(w2.x, tv, accL);
    accR = fmaf(w2.y, tv, accR);
  }
  out[(size_t)(b*2 + 0)*S_LEN + s] = accL;
  out[(size_t)(b*2 + 1)*S_LEN + s] = accR;
}

// ---------------------------------------------------------------------------
extern "C" void kernel_launch(void* const* d_in, const int* in_sizes, int n_in,
                              void* d_out, int out_size, void* d_ws, size_t ws_size,
                              hipStream_t stream) {
  const float* tracks = (const float*)d_in[0];
  const float* mp     = (const float*)d_in[1];
  float* ws  = (float*)d_ws;
  float* out = (float*)d_out;

  hipLaunchKernelGGL(k_setup,  dim3(1),    dim3(64),  0, stream, mp, ws);
  hipLaunchKernelGGL(k_matpow, dim3(64),   dim3(192), 0, stream, ws);
  hipLaunchKernelGGL(k_phase1, dim3(CCH),  dim3(64),  0, stream, tracks, ws);
  hipLaunchKernelGGL(k_scanz,  dim3(1),    dim3(64),  0, stream, ws);
  hipLaunchKernelGGL(k_phase3, dim3(CCH),  dim3(64),  0, stream, tracks, ws);
  hipLaunchKernelGGL(k_smooth, dim3(NTR),  dim3(256), 0, stream, ws);
  hipLaunchKernelGGL(k_mix1,   dim3(NST3/4),  dim3(256), 0, stream, ws);
  hipLaunchKernelGGL(k_mix2,   dim3(S_LEN/64), dim3(256), 0, stream, ws, out);
}